// Round 7
// baseline (202.805 us; speedup 1.0000x reference)
//
#include <hip/hip_runtime.h>
#include <cstdint>

// ---- types ----
typedef __bf16 bf16;
typedef __attribute__((ext_vector_type(8))) __bf16 bf16x8;
typedef __attribute__((ext_vector_type(4))) __bf16 bf16v4;
typedef __attribute__((ext_vector_type(2))) __bf16 bf16x2;
typedef __attribute__((ext_vector_type(4))) float f32x4;
typedef __attribute__((ext_vector_type(16))) float f32x16;
typedef __attribute__((ext_vector_type(4))) unsigned u32x4;

#define MFMA16(a, b, c) __builtin_amdgcn_mfma_f32_16x16x32_bf16((a), (b), (c), 0, 0, 0)
#define MFMA32(a, b, c) __builtin_amdgcn_mfma_f32_32x32x16_bf16((a), (b), (c), 0, 0, 0)

// Problem constants
#define BATCH 2
#define SLEN 2048
#define HDIM 1024
#define NHEAD 16
#define HEADD 64
#define MROWS (BATCH * SLEN)   // 4096

#define CEXP 0.1803368801f     // 0.125 * log2(e), folded into Q at projection

// async global->LDS, 16B per lane. LDS dest is wave-uniform base + lane*16.
typedef __attribute__((address_space(3))) void lds_void;
typedef const __attribute__((address_space(1))) void glb_void;
__device__ __forceinline__ void load_lds16(const bf16* g, bf16* l) {
    __builtin_amdgcn_global_load_lds((glb_void*)g, (lds_void*)l, 16, 0, 0);
}

// cross-half lane exchange: swaps a[lanes 32..63] with b[lanes 0..31]
__device__ __forceinline__ void plswap(unsigned& a, unsigned& b) {
#if __has_builtin(__builtin_amdgcn_permlane32_swap)
    auto r = __builtin_amdgcn_permlane32_swap(a, b, false, false);
    a = r[0]; b = r[1];
#else
    asm volatile("v_permlane32_swap_b32 %0, %1" : "+v"(a), "+v"(b));
#endif
}

// packed f32->bf16 conversion (no scalar bf16 cvt on gfx950).
__device__ __forceinline__ unsigned cvtpk_bf16(float lo, float hi) {
    unsigned r;
    asm("v_cvt_pk_bf16_f32 %0, %1, %2" : "=v"(r) : "v"(lo), "v"(hi));
    return r;
}

// ---------------------------------------------------------------------------
// merged prep kernel: one launch instead of five.
// ---------------------------------------------------------------------------
__global__ __launch_bounds__(256) void prep_kernel(const float* __restrict__ X,
                                                   const float* __restrict__ Wq,
                                                   const float* __restrict__ Wkv,
                                                   const float* __restrict__ Wo,
                                                   const float* __restrict__ bq,
                                                   const float* __restrict__ bkv,
                                                   bf16* __restrict__ Xbf,
                                                   bf16* __restrict__ WqkvT,
                                                   bf16* __restrict__ WoT,
                                                   float* __restrict__ bqkv) {
    const int blk = blockIdx.x;
    const int tid = threadIdx.x;
    if (blk < 4096) {
        int i = (blk * 256 + tid) * 4;
        float4 v = *(const float4*)&X[i];
        bf16v4 o;
        o[0] = (bf16)v.x; o[1] = (bf16)v.y; o[2] = (bf16)v.z; o[3] = (bf16)v.w;
        *(bf16v4*)&Xbf[i] = o;
        return;
    }
    if (blk < 8192) {
        const float* in; bf16* out; int C, id;
        if (blk < 5120)      { in = Wq;  out = WqkvT;                C = 1024; id = blk - 4096; }
        else if (blk < 7168) { in = Wkv; out = WqkvT + 1024 * 1024;  C = 2048; id = blk - 5120; }
        else                 { in = Wo;  out = WoT;                  C = 1024; id = blk - 7168; }
        const int R = 1024;
        const int nbx = C / 32;
        const int j0 = (id % nbx) * 32, i0 = (id / nbx) * 32;
        const int tx = tid & 31, ty = tid >> 5;
        __shared__ float t[32][33];
        for (int r = ty; r < 32; r += 8)
            t[r][tx] = in[(size_t)(i0 + r) * C + j0 + tx];
        __syncthreads();
        for (int r = ty; r < 32; r += 8)
            out[(size_t)(j0 + r) * R + i0 + tx] = (bf16)t[tx][r];
        return;
    }
    int i = (blk - 8192) * 256 + tid;
    if (i < 3072) bqkv[i] = (i < 1024) ? bq[i] : bkv[i - 1024];
}

// ---------------------------------------------------------------------------
// GEMM v2 (round-4 verified structure + T1 XCD grid swizzle): m97-structure,
// T3-minimum 2-phase. Double-buffered LDS; counted vmcnt; lgkmcnt(0) drain
// before the loop-end barrier. The swizzle is a pure bijective index remap
// (nwg % 8 == 0 for both instantiations: 768, 512) — consecutive same-XCD
// blocks share A-panels -> L2 hits instead of L3.
// ---------------------------------------------------------------------------
template <int BM, int BN, int EPI>
__global__ __launch_bounds__(256) void gemm2_kernel(const bf16* __restrict__ A,
                                                    const bf16* __restrict__ BT,
                                                    const float* __restrict__ bias,
                                                    bf16* __restrict__ oQ,
                                                    bf16* __restrict__ oK,
                                                    bf16* __restrict__ oVT,
                                                    float* __restrict__ oF, int K) {
    constexpr int WM = BM / 2, WN = BN / 2;
    constexpr int MT = WM / 16, NT = WN / 16;
    constexpr int NLD = BM / 64 + BN / 64;   // global_load_lds per thread/step

    const int tid = threadIdx.x;
    const int lane = tid & 63, wid = tid >> 6;
    const int l15 = lane & 15, quad = lane >> 4;
    const int wm = (wid >> 1) * WM, wn = (wid & 1) * WN;

    // XCD-aware swizzle: lid -> wg (bijective; hw dispatch is x-fastest,
    // XCD = lid % 8 assumption; if mapping differs only locality changes).
    const int lid = blockIdx.y * gridDim.x + blockIdx.x;
    const int per = (gridDim.x * gridDim.y) >> 3;
    const int wg = (lid & 7) * per + (lid >> 3);
    const int m0 = (wg / gridDim.x) * BM, n0 = (wg % gridDim.x) * BN;

    __shared__ bf16 As[2][BM * 32];
    __shared__ bf16 Bs[2][BN * 32];

    f32x4 acc[MT][NT] = {};

    const bf16* Ag = A + (size_t)m0 * K;
    const bf16* Bg = BT + (size_t)n0 * K;
    const int arow = lane >> 2, acol = (lane & 3) * 8;

#define GSTAGE(buf, k0v) {                                                   \
        _Pragma("unroll")                                                    \
        for (int t = 0; t < BM / 64; ++t) {                                  \
            int tt = t * 4 + wid;                                            \
            load_lds16(Ag + (size_t)(tt * 16 + arow) * K + (k0v) + acol,     \
                       &As[buf][tt * 512]);                                  \
        }                                                                    \
        _Pragma("unroll")                                                    \
        for (int t = 0; t < BN / 64; ++t) {                                  \
            int tt = t * 4 + wid;                                            \
            load_lds16(Bg + (size_t)(tt * 16 + arow) * K + (k0v) + acol,     \
                       &Bs[buf][tt * 512]);                                  \
        }                                                                    \
    }

    GSTAGE(0, 0)

    const int NSTEP = K >> 5;
    for (int s = 0; s < NSTEP; ++s) {
        const int cur = s & 1;
        if (s < NSTEP - 1) {
            GSTAGE(cur ^ 1, (s + 1) * 32)
            // wait only for step s's loads; step s+1's NLD stay in flight
            if constexpr (NLD == 4)
                asm volatile("s_waitcnt vmcnt(4)" ::: "memory");
            else if constexpr (NLD == 3)
                asm volatile("s_waitcnt vmcnt(3)" ::: "memory");
            else
                asm volatile("s_waitcnt vmcnt(2)" ::: "memory");
        } else {
            asm volatile("s_waitcnt vmcnt(0)" ::: "memory");
        }
        __builtin_amdgcn_s_barrier();

        bf16x8 af[MT], bfr[NT];
#pragma unroll
        for (int i = 0; i < MT; ++i)
            af[i] = *(const bf16x8*)&As[cur][(wm + i * 16 + l15) * 32 + quad * 8];
#pragma unroll
        for (int j = 0; j < NT; ++j)
            bfr[j] = *(const bf16x8*)&Bs[cur][(wn + j * 16 + l15) * 32 + quad * 8];
#pragma unroll
        for (int i = 0; i < MT; ++i)
#pragma unroll
            for (int j = 0; j < NT; ++j)
                acc[i][j] = MFMA16(af[i], bfr[j], acc[i][j]);

        // drain LDS reads before the barrier: next iteration's STAGE
        // overwrites buf[cur], and raw s_barrier alone doesn't drain lgkm.
        asm volatile("s_waitcnt lgkmcnt(0)" ::: "memory");
        __builtin_amdgcn_s_barrier();
    }
#undef GSTAGE

    // epilogue (C-layout: row = quad*4+r, col = l15)
#pragma unroll
    for (int i = 0; i < MT; ++i) {
#pragma unroll
        for (int j = 0; j < NT; ++j) {
            const int mb = m0 + wm + i * 16 + quad * 4;
            const int n = n0 + wn + j * 16 + l15;
            const float bv = bias[n];
            if (EPI == 2) {
                float* o = oF + (size_t)mb * 1024 + n;
#pragma unroll
                for (int r = 0; r < 4; ++r) o[(size_t)r * 1024] = acc[i][j][r] + bv;
            } else if (n0 < 1024) {
#pragma unroll
                for (int r = 0; r < 4; ++r)
                    oQ[(size_t)(mb + r) * 1024 + n] = (bf16)((acc[i][j][r] + bv) * CEXP);
            } else if (n0 < 2048) {
#pragma unroll
                for (int r = 0; r < 4; ++r)
                    oK[(size_t)(mb + r) * 1024 + (n - 1024)] = (bf16)(acc[i][j][r] + bv);
            } else {
                const int hd = n - 2048;
                const int bb = mb >> 11, ss = mb & 2047;
                bf16v4 pk;
#pragma unroll
                for (int r = 0; r < 4; ++r) pk[r] = (bf16)(acc[i][j][r] + bv);
                *(bf16v4*)&oVT[((size_t)(bb << 10) + hd) * 2048 + ss] = pk;
            }
        }
    }
}

// ---------------------------------------------------------------------------
// softmax of one 64-key tile (two 32-key sacc subtiles) -> 4 PV B-fragments.
// sacc reg r holds key32 = (r&3) + 8*(r>>2) + 4*hh; PV frag s covers keys
// 16s+8hh+j: words 0/2 = plswap(A[qa],A[qb]), words 1/3 = plswap(B[qa],B[qb]).
// ---------------------------------------------------------------------------
__device__ __forceinline__ void sm_half(f32x16 sa, f32x16 sb, float& l_lane,
                                        bf16x8* pf) {
    unsigned wA[2][4], wB[2][4];
#pragma unroll
    for (int m = 0; m < 2; ++m) {
        const f32x16 s = m ? sb : sa;
#pragma unroll
        for (int g = 0; g < 4; ++g) {
            float p0 = __builtin_amdgcn_exp2f(s[g * 4 + 0]);
            float p1 = __builtin_amdgcn_exp2f(s[g * 4 + 1]);
            float p2 = __builtin_amdgcn_exp2f(s[g * 4 + 2]);
            float p3 = __builtin_amdgcn_exp2f(s[g * 4 + 3]);
            l_lane += (p0 + p1) + (p2 + p3);
            wA[m][g] = cvtpk_bf16(p0, p1);
            wB[m][g] = cvtpk_bf16(p2, p3);
        }
    }
#pragma unroll
    for (int s = 0; s < 4; ++s) {
        const int m = s >> 1, qa = (s & 1) * 2, qb = qa + 1;
        unsigned x0 = wA[m][qa], x2 = wA[m][qb];
        unsigned x1 = wB[m][qa], x3 = wB[m][qb];
        plswap(x0, x2);
        plswap(x1, x3);
        u32x4 fw;
        fw[0] = x0; fw[1] = x1; fw[2] = x2; fw[3] = x3;
        pf[s] = __builtin_bit_cast(bf16x8, fw);
    }
}

// ---------------------------------------------------------------------------
// Flash attention v10b: cross-block key-split, SPILL-SAFE.
// Round-6 diagnosis: v10's __launch_bounds__(256,4) forced VGPR<=128 with
// ~150 live -> scratch spills -> spill buffer_load/store increment vmcnt ->
// hand-counted s_waitcnt vmcnt(4) released waves while tile DMAs were still
// in flight -> stale-LDS reads (nondeterministic few-%% errors). Fix: NO
// min-waves hint (natural allocation ~96-112 VGPR; v8 compiled to 128 with
// 32 MORE live regs). Counted-vmcnt requires a spill-free loop — invariant
// documented here.
// Structure: each block = v8 clone at half scale (256 thr / 4 waves, q-tile
// 128, 16 x 64-key tiles of one 1024-key split). LDS 32KB -> 4 blocks/CU,
// grid 1024 = exactly 4/CU = 4 waves/SIMD (2x v8 TLP). No cross-wave combine
// in-kernel; fp32 partials to workspace, tiny combine kernel follows.
// ---------------------------------------------------------------------------
__global__ __launch_bounds__(256) void attn10_kernel(const bf16* __restrict__ Q,
                                                     const bf16* __restrict__ K,
                                                     const bf16* __restrict__ VT,
                                                     float* __restrict__ Opart,
                                                     float* __restrict__ Lpart) {
    const int bid = blockIdx.x;
    const int xcd = bid & 7, j = bid >> 3;          // j in 0..127
    const int bh = xcd * 4 + (j >> 5);              // per-XCD bh stripe
    const int rest = j & 31;
    const int split = rest >> 4;                    // key half: 0 or 1
    const int q0 = (rest & 15) * 128;
    const int b = bh >> 4, head = bh & 15;
    const int tid = threadIdx.x;
    const int lane = tid & 63, wid = tid >> 6;
    const int l31 = lane & 31, hh = lane >> 5;

    __shared__ bf16 Ks[2][64 * 64];    // [buf][key][d]   row = 128B, XOR-swizzled
    __shared__ bf16 VTs[2][64 * 64];   // [buf][d][key]   row = 128B, XOR-swizzled

    // Q B-frags: B[k=d][n=q]: n = lane&31, k = kd*16 + hh*8 + e
    const int qw = q0 + wid * 32;
    bf16x8 qf[4];
#pragma unroll
    for (int kd = 0; kd < 4; ++kd)
        qf[kd] = *(const bf16x8*)&Q[(size_t)(b * SLEN + qw + l31) * HDIM +
                                    head * 64 + kd * 16 + hh * 8];

    f32x16 o_acc[2] = {};
    const f32x16 ZC = {};   // persistent zero C-operand for QK chain heads
    float l_lane = 0.f;

    const bf16* Kg = K + (size_t)b * SLEN * HDIM + head * 64;
    const bf16* Vg = VT + (size_t)bh * 64 * SLEN;

    // staging lane geometry: 8 rows x 8 chunks of 16B per wave-instr
    const int r8 = lane >> 3, p8 = lane & 7;

    // phase stagger among the 4 co-resident blocks (key order commutes).
    const int ph = (j & 3) << 2;
    const int kbase = split * 1024;

#define STAGE(buf, ktv) {                                                          \
        const int k0_ = kbase + (((ktv) + ph) & 15) * 64;                          \
        _Pragma("unroll")                                                          \
        for (int pass = 0; pass < 2; ++pass) {                                     \
            const int rbk = pass * 32 + wid * 8;                                   \
            load_lds16(Kg + (size_t)(k0_ + rbk + r8) * HDIM +                      \
                           ((p8 ^ ((rbk + r8) & 7)) * 8),                          \
                       &Ks[buf][rbk * 64]);                                        \
            const int rbv = pass * 32 + wid * 8;                                   \
            load_lds16(Vg + (size_t)(rbv + r8) * SLEN + k0_ +                      \
                           ((p8 ^ ((rbv + r8) & 7)) * 8),                          \
                       &VTs[buf][rbv * 64]);                                       \
        } }

    STAGE(0, 0)

    for (int kt = 0; kt < 16; ++kt) {
        const int cur = kt & 1;
        if (kt < 15) {
            STAGE(cur ^ 1, kt + 1)
            asm volatile("s_waitcnt vmcnt(4)" ::: "memory");
        } else {
            asm volatile("s_waitcnt vmcnt(0)" ::: "memory");
        }
        __builtin_amdgcn_s_barrier();

        const bf16* Kc = &Ks[cur][0];
        const bf16* Vc = &VTs[cur][0];

        // ---- QK^T over this 64-key tile (8 MFMA, 2 chains) ----
        f32x16 s0, s1;
        __builtin_amdgcn_s_setprio(1);
#define QK_STEP(sv, m, kd, Cin) {                                          \
        const int key_ = (m) * 32 + l31;                                   \
        const int c_ = ((kd) * 2 + hh) ^ (key_ & 7);                       \
        bf16x8 kf_ = *(const bf16x8*)&Kc[key_ * 64 + c_ * 8];              \
        sv = MFMA32(kf_, qf[kd], Cin); }
        QK_STEP(s0, 0, 0, ZC)
        QK_STEP(s1, 1, 0, ZC)
#pragma unroll
        for (int kd = 1; kd < 4; ++kd) {
            QK_STEP(s0, 0, kd, s0)
            QK_STEP(s1, 1, kd, s1)
        }
        __builtin_amdgcn_s_setprio(0);

        // ---- softmax (VALU) under QK drain ----
        bf16x8 pf[4];
        sm_half(s0, s1, l_lane, pf);

        // ---- PV (8 MFMA) ----
        __builtin_amdgcn_s_setprio(1);
#pragma unroll
        for (int s = 0; s < 4; ++s)
#pragma unroll
            for (int dt = 0; dt < 2; ++dt) {
                const int d = dt * 32 + l31;
                const int cc = (s * 2 + hh) ^ (d & 7);
                bf16x8 vf = *(const bf16x8*)&Vc[d * 64 + cc * 8];
                o_acc[dt] = MFMA32(vf, pf[s], o_acc[dt]);
            }
        __builtin_amdgcn_s_setprio(0);

        // drain this tile's ds_reads + pin consumers before the barrier
        // (rule #18: next STAGE DMA overwrites buf[cur]).
        asm volatile("s_waitcnt lgkmcnt(0)" ::: "memory");
        __builtin_amdgcn_sched_barrier(0);
        __builtin_amdgcn_s_barrier();
    }

    // ---- epilogue: write partial (o, l) for this split ----
    const float l_half = l_lane + __shfl_xor(l_lane, 32, 64);

    const int qrow = (bh << 11) + qw + l31;         // 0..65535
    float* op = Opart + ((size_t)split << 22) + (size_t)qrow * 64;
#pragma unroll
    for (int mt = 0; mt < 2; ++mt)
#pragma unroll
        for (int gq = 0; gq < 4; ++gq) {
            float4 v4;
            v4.x = o_acc[mt][gq * 4 + 0];
            v4.y = o_acc[mt][gq * 4 + 1];
            v4.z = o_acc[mt][gq * 4 + 2];
            v4.w = o_acc[mt][gq * 4 + 3];
            *(float4*)&op[mt * 32 + gq * 8 + 4 * hh] = v4;
        }
    if (hh == 0) Lpart[(split << 16) + qrow] = l_half;
}

// ---------------------------------------------------------------------------
// combine: A = (o0 + o1) / (l0 + l1), fp32 partials -> bf16 attn output.
// 1,048,576 threads, one float4-slot each; fully coalesced on both sides.
// ---------------------------------------------------------------------------
__global__ __launch_bounds__(256) void combine_kernel(const float* __restrict__ Opart,
                                                      const float* __restrict__ Lpart,
                                                      bf16* __restrict__ A) {
    const int idx = blockIdx.x * 256 + threadIdx.x;   // 0..1048575
    const int qrow = idx >> 4, dq = (idx & 15) << 2;
    const float l = Lpart[qrow] + Lpart[(1 << 16) + qrow];
    const float4 a = *(const float4*)&Opart[(size_t)idx * 4];
    const float4 c = *(const float4*)&Opart[(1ull << 22) + (size_t)idx * 4];
    const float inv = 1.f / l;
    bf16v4 o;
    o[0] = (bf16)((a.x + c.x) * inv);
    o[1] = (bf16)((a.y + c.y) * inv);
    o[2] = (bf16)((a.z + c.z) * inv);
    o[3] = (bf16)((a.w + c.w) * inv);
    const int bh = qrow >> 11, q = qrow & 2047;
    *(bf16v4*)&A[((size_t)((bh >> 4) * SLEN + q)) * HDIM + (bh & 15) * 64 + dq] = o;
}

// ---------------------------------------------------------------------------
// launch
// ---------------------------------------------------------------------------
extern "C" void kernel_launch(void* const* d_in, const int* in_sizes, int n_in,
                              void* d_out, int out_size, void* d_ws, size_t ws_size,
                              hipStream_t stream) {
    const float* X   = (const float*)d_in[0];
    const float* Wq  = (const float*)d_in[1];
    const float* bq  = (const float*)d_in[2];
    const float* Wkv = (const float*)d_in[3];
    const float* bkv = (const float*)d_in[4];
    const float* Wo  = (const float*)d_in[5];
    const float* bo  = (const float*)d_in[6];
    float* out = (float*)d_out;

    char* ws = (char*)d_ws;
    bf16* Xbf   = (bf16*)(ws);                     // 8 MB  (4096x1024)
    bf16* WqkvT = (bf16*)(ws + (8ull << 20));      // 6 MB  (3072x1024)
    bf16* WoT   = (bf16*)(ws + (14ull << 20));     // 2 MB  (1024x1024)
    float* bqkv = (float*)(ws + (16ull << 20));    // 12 KB (3072)
    bf16* Qbf   = (bf16*)(ws + (17ull << 20));     // 8 MB (pre-scaled by CEXP)
    bf16* Kbf   = (bf16*)(ws + (25ull << 20));     // 8 MB
    bf16* VTbf  = (bf16*)(ws + (33ull << 20));     // 8 MB (per-head transposed V)
    bf16* Abf   = (bf16*)(ws + (41ull << 20));     // 8 MB
    float* Opart = (float*)(ws + (49ull << 20));   // 32 MB (2 splits x 16 MB)
    float* Lpart = (float*)(ws + (81ull << 20));   // 512 KB (2 x 65536 f32)

    // merged prep (1 launch)
    prep_kernel<<<8204, 256, 0, stream>>>(X, Wq, Wkv, Wo, bq, bkv, Xbf, WqkvT, WoT, bqkv);

    // fused QKV projection: (4096x1024) @ (1024x3072), 2-phase + XCD swizzle
    gemm2_kernel<128, 128, 1><<<dim3(3072 / 128, MROWS / 128), 256, 0, stream>>>(
        Xbf, WqkvT, bqkv, Qbf, Kbf, VTbf, nullptr, 1024);

    // flash attention (cross-block key-split, spill-safe, 4 waves/SIMD)
    attn10_kernel<<<1024, 256, 0, stream>>>(Qbf, Kbf, VTbf, Opart, Lpart);
    combine_kernel<<<4096, 256, 0, stream>>>(Opart, Lpart, Abf);

    // output projection: (4096x1024) @ (1024x1024) + bo -> fp32, 2-phase + swizzle
    gemm2_kernel<128, 64, 2><<<dim3(1024 / 64, MROWS / 128), 256, 0, stream>>>(
        Abf, WoT, bo, nullptr, nullptr, nullptr, out, 1024);
}

// Round 8
// 189.621 us; speedup vs baseline: 1.0695x; 1.0695x over previous
//
#include <hip/hip_runtime.h>
#include <cstdint>

// ---- types ----
typedef __bf16 bf16;
typedef __attribute__((ext_vector_type(8))) __bf16 bf16x8;
typedef __attribute__((ext_vector_type(4))) __bf16 bf16v4;
typedef __attribute__((ext_vector_type(2))) __bf16 bf16x2;
typedef __attribute__((ext_vector_type(4))) float f32x4;
typedef __attribute__((ext_vector_type(16))) float f32x16;
typedef __attribute__((ext_vector_type(4))) unsigned u32x4;

#define MFMA16(a, b, c) __builtin_amdgcn_mfma_f32_16x16x32_bf16((a), (b), (c), 0, 0, 0)
#define MFMA32(a, b, c) __builtin_amdgcn_mfma_f32_32x32x16_bf16((a), (b), (c), 0, 0, 0)

// Problem constants
#define BATCH 2
#define SLEN 2048
#define HDIM 1024
#define NHEAD 16
#define HEADD 64
#define MROWS (BATCH * SLEN)   // 4096

#define CEXP 0.1803368801f     // 0.125 * log2(e), folded into Q at projection

// async global->LDS, 16B per lane. LDS dest is wave-uniform base + lane*16.
typedef __attribute__((address_space(3))) void lds_void;
typedef const __attribute__((address_space(1))) void glb_void;
__device__ __forceinline__ void load_lds16(const bf16* g, bf16* l) {
    __builtin_amdgcn_global_load_lds((glb_void*)g, (lds_void*)l, 16, 0, 0);
}

// cross-half lane exchange: swaps a[lanes 32..63] with b[lanes 0..31]
__device__ __forceinline__ void plswap(unsigned& a, unsigned& b) {
#if __has_builtin(__builtin_amdgcn_permlane32_swap)
    auto r = __builtin_amdgcn_permlane32_swap(a, b, false, false);
    a = r[0]; b = r[1];
#else
    asm volatile("v_permlane32_swap_b32 %0, %1" : "+v"(a), "+v"(b));
#endif
}

// packed f32->bf16 conversion (no scalar bf16 cvt on gfx950).
__device__ __forceinline__ unsigned cvtpk_bf16(float lo, float hi) {
    unsigned r;
    asm("v_cvt_pk_bf16_f32 %0, %1, %2" : "=v"(r) : "v"(lo), "v"(hi));
    return r;
}

// ---------------------------------------------------------------------------
// merged prep kernel: one launch instead of five.
// ---------------------------------------------------------------------------
__global__ __launch_bounds__(256) void prep_kernel(const float* __restrict__ X,
                                                   const float* __restrict__ Wq,
                                                   const float* __restrict__ Wkv,
                                                   const float* __restrict__ Wo,
                                                   const float* __restrict__ bq,
                                                   const float* __restrict__ bkv,
                                                   bf16* __restrict__ Xbf,
                                                   bf16* __restrict__ WqkvT,
                                                   bf16* __restrict__ WoT,
                                                   float* __restrict__ bqkv) {
    const int blk = blockIdx.x;
    const int tid = threadIdx.x;
    if (blk < 4096) {
        int i = (blk * 256 + tid) * 4;
        float4 v = *(const float4*)&X[i];
        bf16v4 o;
        o[0] = (bf16)v.x; o[1] = (bf16)v.y; o[2] = (bf16)v.z; o[3] = (bf16)v.w;
        *(bf16v4*)&Xbf[i] = o;
        return;
    }
    if (blk < 8192) {
        const float* in; bf16* out; int C, id;
        if (blk < 5120)      { in = Wq;  out = WqkvT;                C = 1024; id = blk - 4096; }
        else if (blk < 7168) { in = Wkv; out = WqkvT + 1024 * 1024;  C = 2048; id = blk - 5120; }
        else                 { in = Wo;  out = WoT;                  C = 1024; id = blk - 7168; }
        const int R = 1024;
        const int nbx = C / 32;
        const int j0 = (id % nbx) * 32, i0 = (id / nbx) * 32;
        const int tx = tid & 31, ty = tid >> 5;
        __shared__ float t[32][33];
        for (int r = ty; r < 32; r += 8)
            t[r][tx] = in[(size_t)(i0 + r) * C + j0 + tx];
        __syncthreads();
        for (int r = ty; r < 32; r += 8)
            out[(size_t)(j0 + r) * R + i0 + tx] = (bf16)t[tx][r];
        return;
    }
    int i = (blk - 8192) * 256 + tid;
    if (i < 3072) bqkv[i] = (i < 1024) ? bq[i] : bkv[i - 1024];
}

// ---------------------------------------------------------------------------
// GEMM v2 (round-4 verified structure + T1 XCD grid swizzle, as passed in
// round 7): m97-structure, T3-minimum 2-phase. Double-buffered LDS; counted
// vmcnt; lgkmcnt(0) drain before the loop-end barrier (raw s_barrier does
// not drain counters). Swizzle is a bijective index remap (nwg%8==0 for
// both instantiations: 768, 512).
// ---------------------------------------------------------------------------
template <int BM, int BN, int EPI>
__global__ __launch_bounds__(256) void gemm2_kernel(const bf16* __restrict__ A,
                                                    const bf16* __restrict__ BT,
                                                    const float* __restrict__ bias,
                                                    bf16* __restrict__ oQ,
                                                    bf16* __restrict__ oK,
                                                    bf16* __restrict__ oVT,
                                                    float* __restrict__ oF, int K) {
    constexpr int WM = BM / 2, WN = BN / 2;
    constexpr int MT = WM / 16, NT = WN / 16;
    constexpr int NLD = BM / 64 + BN / 64;   // global_load_lds per thread/step

    const int tid = threadIdx.x;
    const int lane = tid & 63, wid = tid >> 6;
    const int l15 = lane & 15, quad = lane >> 4;
    const int wm = (wid >> 1) * WM, wn = (wid & 1) * WN;

    // XCD-aware swizzle: lid -> wg (bijective).
    const int lid = blockIdx.y * gridDim.x + blockIdx.x;
    const int per = (gridDim.x * gridDim.y) >> 3;
    const int wg = (lid & 7) * per + (lid >> 3);
    const int m0 = (wg / gridDim.x) * BM, n0 = (wg % gridDim.x) * BN;

    __shared__ bf16 As[2][BM * 32];
    __shared__ bf16 Bs[2][BN * 32];

    f32x4 acc[MT][NT] = {};

    const bf16* Ag = A + (size_t)m0 * K;
    const bf16* Bg = BT + (size_t)n0 * K;
    const int arow = lane >> 2, acol = (lane & 3) * 8;

#define GSTAGE(buf, k0v) {                                                   \
        _Pragma("unroll")                                                    \
        for (int t = 0; t < BM / 64; ++t) {                                  \
            int tt = t * 4 + wid;                                            \
            load_lds16(Ag + (size_t)(tt * 16 + arow) * K + (k0v) + acol,     \
                       &As[buf][tt * 512]);                                  \
        }                                                                    \
        _Pragma("unroll")                                                    \
        for (int t = 0; t < BN / 64; ++t) {                                  \
            int tt = t * 4 + wid;                                            \
            load_lds16(Bg + (size_t)(tt * 16 + arow) * K + (k0v) + acol,     \
                       &Bs[buf][tt * 512]);                                  \
        }                                                                    \
    }

    GSTAGE(0, 0)

    const int NSTEP = K >> 5;
    for (int s = 0; s < NSTEP; ++s) {
        const int cur = s & 1;
        if (s < NSTEP - 1) {
            GSTAGE(cur ^ 1, (s + 1) * 32)
            // wait only for step s's loads; step s+1's NLD stay in flight
            if constexpr (NLD == 4)
                asm volatile("s_waitcnt vmcnt(4)" ::: "memory");
            else if constexpr (NLD == 3)
                asm volatile("s_waitcnt vmcnt(3)" ::: "memory");
            else
                asm volatile("s_waitcnt vmcnt(2)" ::: "memory");
        } else {
            asm volatile("s_waitcnt vmcnt(0)" ::: "memory");
        }
        __builtin_amdgcn_s_barrier();

        bf16x8 af[MT], bfr[NT];
#pragma unroll
        for (int i = 0; i < MT; ++i)
            af[i] = *(const bf16x8*)&As[cur][(wm + i * 16 + l15) * 32 + quad * 8];
#pragma unroll
        for (int j = 0; j < NT; ++j)
            bfr[j] = *(const bf16x8*)&Bs[cur][(wn + j * 16 + l15) * 32 + quad * 8];
#pragma unroll
        for (int i = 0; i < MT; ++i)
#pragma unroll
            for (int j = 0; j < NT; ++j)
                acc[i][j] = MFMA16(af[i], bfr[j], acc[i][j]);

        // drain LDS reads before the barrier: next iteration's STAGE
        // overwrites buf[cur], and raw s_barrier alone doesn't drain lgkm.
        asm volatile("s_waitcnt lgkmcnt(0)" ::: "memory");
        __builtin_amdgcn_s_barrier();
    }
#undef GSTAGE

    // epilogue (C-layout: row = quad*4+r, col = l15)
#pragma unroll
    for (int i = 0; i < MT; ++i) {
#pragma unroll
        for (int j = 0; j < NT; ++j) {
            const int mb = m0 + wm + i * 16 + quad * 4;
            const int n = n0 + wn + j * 16 + l15;
            const float bv = bias[n];
            if (EPI == 2) {
                float* o = oF + (size_t)mb * 1024 + n;
#pragma unroll
                for (int r = 0; r < 4; ++r) o[(size_t)r * 1024] = acc[i][j][r] + bv;
            } else if (n0 < 1024) {
#pragma unroll
                for (int r = 0; r < 4; ++r)
                    oQ[(size_t)(mb + r) * 1024 + n] = (bf16)((acc[i][j][r] + bv) * CEXP);
            } else if (n0 < 2048) {
#pragma unroll
                for (int r = 0; r < 4; ++r)
                    oK[(size_t)(mb + r) * 1024 + (n - 1024)] = (bf16)(acc[i][j][r] + bv);
            } else {
                const int hd = n - 2048;
                const int bb = mb >> 11, ss = mb & 2047;
                bf16v4 pk;
#pragma unroll
                for (int r = 0; r < 4; ++r) pk[r] = (bf16)(acc[i][j][r] + bv);
                *(bf16v4*)&oVT[((size_t)(bb << 10) + hd) * 2048 + ss] = pk;
            }
        }
    }
}

// ---------------------------------------------------------------------------
// softmax of one 64-key half (two 32-key sacc tiles) -> 4 PV B-fragments.
// sacc reg r holds key32 = (r&3) + 8*(r>>2) + 4*hh; PV frag s covers keys
// 16s+8hh+j: words 0/2 = plswap(A[qa],A[qb]), words 1/3 = plswap(B[qa],B[qb]).
// ---------------------------------------------------------------------------
__device__ __forceinline__ void sm_half(f32x16 sa, f32x16 sb, float& l_lane,
                                        bf16x8* pf) {
    unsigned wA[2][4], wB[2][4];
#pragma unroll
    for (int m = 0; m < 2; ++m) {
        const f32x16 s = m ? sb : sa;
#pragma unroll
        for (int g = 0; g < 4; ++g) {
            float p0 = __builtin_amdgcn_exp2f(s[g * 4 + 0]);
            float p1 = __builtin_amdgcn_exp2f(s[g * 4 + 1]);
            float p2 = __builtin_amdgcn_exp2f(s[g * 4 + 2]);
            float p3 = __builtin_amdgcn_exp2f(s[g * 4 + 3]);
            l_lane += (p0 + p1) + (p2 + p3);
            wA[m][g] = cvtpk_bf16(p0, p1);
            wB[m][g] = cvtpk_bf16(p2, p3);
        }
    }
#pragma unroll
    for (int s = 0; s < 4; ++s) {
        const int m = s >> 1, qa = (s & 1) * 2, qb = qa + 1;
        unsigned x0 = wA[m][qa], x2 = wA[m][qb];
        unsigned x1 = wB[m][qa], x3 = wB[m][qb];
        plswap(x0, x2);
        plswap(x1, x3);
        u32x4 fw;
        fw[0] = x0; fw[1] = x1; fw[2] = x2; fw[3] = x3;
        pf[s] = __builtin_bit_cast(bf16x8, fw);
    }
}

// ---------------------------------------------------------------------------
// Flash attention v8 (twice-verified: rounds 2 and 4, 52.0 µs): intra-wave
// pipe overlap, 4 waves/block, 2 waves/SIMD. Round-7 evidence: raising
// blocks/CU to 4 did NOT raise achieved occupancy or speed — the residual
// stall is dependency-serial (sm chain + MFMA chains + barrier convoy),
// which this structure's intra-wave interleave already attacks. ~52 µs is
// this decomposition's structural floor.
// ---------------------------------------------------------------------------
__global__ __launch_bounds__(256) void attn8_kernel(const bf16* __restrict__ Q,
                                                    const bf16* __restrict__ K,
                                                    const bf16* __restrict__ VT,
                                                    bf16* __restrict__ O) {
    const int bid = blockIdx.x;
    const int xcd = bid & 7, j = bid >> 3;
    const int bh = xcd * 4 + (j >> 4);        // per-XCD bh stripe
    const int q0 = (j & 15) * 128;
    const int b = bh >> 4, head = bh & 15;
    const int tid = threadIdx.x;
    const int lane = tid & 63, wid = tid >> 6;
    const int l31 = lane & 31, hh = lane >> 5;

    __shared__ bf16 Ks[2][128 * 64];    // [buf][key][d]   row = 128B, XOR-swizzled
    __shared__ bf16 VTs[2][64 * 128];   // [buf][d][key]   row = 256B, XOR-swizzled

    // Q B-frags: B[k=d][n=q]: n = lane&31, k = kd*16 + hh*8 + j
    const int qw = q0 + wid * 32;
    bf16x8 qf[4];
#pragma unroll
    for (int kd = 0; kd < 4; ++kd)
        qf[kd] = *(const bf16x8*)&Q[(size_t)(b * SLEN + qw + l31) * HDIM +
                                    head * 64 + kd * 16 + hh * 8];

    f32x16 o_acc[2] = {};
    const f32x16 ZC = {};   // persistent zero C-operand for QK chain heads
    float l_lane = 0.f;

    const bf16* Kg = K + (size_t)b * SLEN * HDIM + head * 64;
    const bf16* Vg = VT + (size_t)bh * 64 * SLEN;

    // staging lane geometry
    const int r8 = lane >> 3, p8 = lane & 7;     // K: 8 rows x 8 chunks / instr
    const int r16 = lane >> 4, p16 = lane & 15;  // V: 4 rows x 16 chunks / instr

    // barrier-convoy desync between the two co-resident blocks per CU:
    // rotate the key-tile walk (key order is sum-commutative).
    const int ph = (j & 1) << 3;

#define STAGE(buf, ktv) {                                                          \
        const int k0_ = (((ktv) + ph) & 15) * 128;                                 \
        _Pragma("unroll")                                                          \
        for (int pass = 0; pass < 4; ++pass) {                                     \
            const int rbk = pass * 32 + wid * 8;                                   \
            load_lds16(Kg + (size_t)(k0_ + rbk + r8) * HDIM +                      \
                           ((p8 ^ ((rbk + r8) & 7)) * 8),                          \
                       &Ks[buf][rbk * 64]);                                        \
            const int rbv = pass * 16 + wid * 4;                                   \
            load_lds16(Vg + (size_t)(rbv + r16) * SLEN + k0_ +                     \
                           ((p16 ^ ((rbv + r16) & 15)) * 8),                       \
                       &VTs[buf][rbv * 128]);                                      \
        } }

    STAGE(0, 0)

    for (int kt = 0; kt < 16; ++kt) {
        const int cur = kt & 1;
        if (kt < 15) {
            STAGE(cur ^ 1, kt + 1)
            asm volatile("s_waitcnt vmcnt(8)" ::: "memory");
        } else {
            asm volatile("s_waitcnt vmcnt(0)" ::: "memory");
        }
        __builtin_amdgcn_s_barrier();

        const bf16* Kc = &Ks[cur][0];
        const bf16* Vc = &VTs[cur][0];

        // ---- QK^T, BOTH 64-key halves up front (4 independent chains) ----
        f32x16 s00, s01, s10, s11;
        __builtin_amdgcn_s_setprio(1);
#define QK_STEP(sv, h, m, kd, Cin) {                                       \
        const int key_ = ((h) * 2 + (m)) * 32 + l31;                       \
        const int c_ = ((kd) * 2 + hh) ^ (key_ & 7);                       \
        bf16x8 kf_ = *(const bf16x8*)&Kc[key_ * 64 + c_ * 8];              \
        sv = MFMA32(kf_, qf[kd], Cin); }
        QK_STEP(s00, 0, 0, 0, ZC)
        QK_STEP(s01, 0, 1, 0, ZC)
        QK_STEP(s10, 1, 0, 0, ZC)
        QK_STEP(s11, 1, 1, 0, ZC)
#pragma unroll
        for (int kd = 1; kd < 4; ++kd) {
            QK_STEP(s00, 0, 0, kd, s00)
            QK_STEP(s01, 0, 1, kd, s01)
            QK_STEP(s10, 1, 0, kd, s10)
            QK_STEP(s11, 1, 1, kd, s11)
        }
        __builtin_amdgcn_s_setprio(0);

        // ---- softmax h=0 (VALU) under QK h=1 MFMA drain ----
        bf16x8 pf0[4], pf1[4];
        sm_half(s00, s01, l_lane, pf0);

        // ---- PV h=0 (8 MFMA) ----
        __builtin_amdgcn_s_setprio(1);
#pragma unroll
        for (int s = 0; s < 4; ++s)
#pragma unroll
            for (int dt = 0; dt < 2; ++dt) {
                const int d = dt * 32 + l31;
                const int cc = (s * 2 + hh) ^ (d & 15);
                bf16x8 vf = *(const bf16x8*)&Vc[d * 128 + cc * 8];
                o_acc[dt] = MFMA32(vf, pf0[s], o_acc[dt]);
            }
        __builtin_amdgcn_s_setprio(0);

        // ---- softmax h=1 (VALU) under PV h=0 MFMA drain ----
        sm_half(s10, s11, l_lane, pf1);

        // ---- PV h=1 (8 MFMA) ----
        __builtin_amdgcn_s_setprio(1);
#pragma unroll
        for (int s = 0; s < 4; ++s)
#pragma unroll
            for (int dt = 0; dt < 2; ++dt) {
                const int d = dt * 32 + l31;
                const int cc = ((4 + s) * 2 + hh) ^ (d & 15);
                bf16x8 vf = *(const bf16x8*)&Vc[d * 128 + cc * 8];
                o_acc[dt] = MFMA32(vf, pf1[s], o_acc[dt]);
            }
        __builtin_amdgcn_s_setprio(0);

        asm volatile("" ::: "memory");
        __builtin_amdgcn_s_barrier();
    }

    // epilogue: l = own half + other key-half (lane^32 has same query col)
    const float l_full = l_lane + __shfl_xor(l_lane, 32, 64);
    const float inv = 1.f / l_full;
    bf16* orow = O + (size_t)(b * SLEN + qw + l31) * HDIM + head * 64;
#pragma unroll
    for (int mt = 0; mt < 2; ++mt)
#pragma unroll
        for (int g = 0; g < 4; ++g) {
            bf16v4 pk;
#pragma unroll
            for (int r = 0; r < 4; ++r) pk[r] = (bf16)(o_acc[mt][g * 4 + r] * inv);
            *(bf16v4*)&orow[mt * 32 + g * 8 + 4 * hh] = pk;
        }
}

// ---------------------------------------------------------------------------
// launch
// ---------------------------------------------------------------------------
extern "C" void kernel_launch(void* const* d_in, const int* in_sizes, int n_in,
                              void* d_out, int out_size, void* d_ws, size_t ws_size,
                              hipStream_t stream) {
    const float* X   = (const float*)d_in[0];
    const float* Wq  = (const float*)d_in[1];
    const float* bq  = (const float*)d_in[2];
    const float* Wkv = (const float*)d_in[3];
    const float* bkv = (const float*)d_in[4];
    const float* Wo  = (const float*)d_in[5];
    const float* bo  = (const float*)d_in[6];
    float* out = (float*)d_out;

    char* ws = (char*)d_ws;
    bf16* Xbf   = (bf16*)(ws);                     // 8 MB  (4096x1024)
    bf16* WqkvT = (bf16*)(ws + (8ull << 20));      // 6 MB  (3072x1024)
    bf16* WoT   = (bf16*)(ws + (14ull << 20));     // 2 MB  (1024x1024)
    float* bqkv = (float*)(ws + (16ull << 20));    // 12 KB (3072)
    bf16* Qbf   = (bf16*)(ws + (17ull << 20));     // 8 MB (pre-scaled by CEXP)
    bf16* Kbf   = (bf16*)(ws + (25ull << 20));     // 8 MB
    bf16* VTbf  = (bf16*)(ws + (33ull << 20));     // 8 MB (per-head transposed V)
    bf16* Abf   = (bf16*)(ws + (41ull << 20));     // 8 MB

    // merged prep (1 launch)
    prep_kernel<<<8204, 256, 0, stream>>>(X, Wq, Wkv, Wo, bq, bkv, Xbf, WqkvT, WoT, bqkv);

    // fused QKV projection: (4096x1024) @ (1024x3072), 2-phase + XCD swizzle
    gemm2_kernel<128, 128, 1><<<dim3(3072 / 128, MROWS / 128), 256, 0, stream>>>(
        Xbf, WqkvT, bqkv, Qbf, Kbf, VTbf, nullptr, 1024);

    // flash attention (verified v8)
    attn8_kernel<<<512, 256, 0, stream>>>(Qbf, Kbf, VTbf, Abf);

    // output projection: (4096x1024) @ (1024x1024) + bo -> fp32, 2-phase + swizzle
    gemm2_kernel<128, 64, 2><<<dim3(1024 / 64, MROWS / 128), 256, 0, stream>>>(
        Abf, WoT, bo, nullptr, nullptr, nullptr, out, 1024);
}

// Round 11
// 189.167 us; speedup vs baseline: 1.0721x; 1.0024x over previous
//
#include <hip/hip_runtime.h>
#include <cstdint>

// ---- types ----
typedef __bf16 bf16;
typedef __attribute__((ext_vector_type(8))) __bf16 bf16x8;
typedef __attribute__((ext_vector_type(4))) __bf16 bf16v4;
typedef __attribute__((ext_vector_type(2))) __bf16 bf16x2;
typedef __attribute__((ext_vector_type(4))) float f32x4;
typedef __attribute__((ext_vector_type(16))) float f32x16;
typedef __attribute__((ext_vector_type(4))) unsigned u32x4;

#define MFMA16(a, b, c) __builtin_amdgcn_mfma_f32_16x16x32_bf16((a), (b), (c), 0, 0, 0)
#define MFMA32(a, b, c) __builtin_amdgcn_mfma_f32_32x32x16_bf16((a), (b), (c), 0, 0, 0)

// Problem constants
#define BATCH 2
#define SLEN 2048
#define HDIM 1024
#define NHEAD 16
#define HEADD 64
#define MROWS (BATCH * SLEN)   // 4096

#define CEXP 0.1803368801f     // 0.125 * log2(e), folded into Q at projection

// async global->LDS, 16B per lane. LDS dest is wave-uniform base + lane*16.
typedef __attribute__((address_space(3))) void lds_void;
typedef const __attribute__((address_space(1))) void glb_void;
__device__ __forceinline__ void load_lds16(const bf16* g, bf16* l) {
    __builtin_amdgcn_global_load_lds((glb_void*)g, (lds_void*)l, 16, 0, 0);
}

// cross-half lane exchange: swaps a[lanes 32..63] with b[lanes 0..31]
__device__ __forceinline__ void plswap(unsigned& a, unsigned& b) {
#if __has_builtin(__builtin_amdgcn_permlane32_swap)
    auto r = __builtin_amdgcn_permlane32_swap(a, b, false, false);
    a = r[0]; b = r[1];
#else
    asm volatile("v_permlane32_swap_b32 %0, %1" : "+v"(a), "+v"(b));
#endif
}

// packed f32->bf16 conversion (no scalar bf16 cvt on gfx950).
__device__ __forceinline__ unsigned cvtpk_bf16(float lo, float hi) {
    unsigned r;
    asm("v_cvt_pk_bf16_f32 %0, %1, %2" : "=v"(r) : "v"(lo), "v"(hi));
    return r;
}

// ---------------------------------------------------------------------------
// merged prep kernel: one launch instead of five.
// ---------------------------------------------------------------------------
__global__ __launch_bounds__(256) void prep_kernel(const float* __restrict__ X,
                                                   const float* __restrict__ Wq,
                                                   const float* __restrict__ Wkv,
                                                   const float* __restrict__ Wo,
                                                   const float* __restrict__ bq,
                                                   const float* __restrict__ bkv,
                                                   bf16* __restrict__ Xbf,
                                                   bf16* __restrict__ WqkvT,
                                                   bf16* __restrict__ WoT,
                                                   float* __restrict__ bqkv) {
    const int blk = blockIdx.x;
    const int tid = threadIdx.x;
    if (blk < 4096) {
        int i = (blk * 256 + tid) * 4;
        float4 v = *(const float4*)&X[i];
        bf16v4 o;
        o[0] = (bf16)v.x; o[1] = (bf16)v.y; o[2] = (bf16)v.z; o[3] = (bf16)v.w;
        *(bf16v4*)&Xbf[i] = o;
        return;
    }
    if (blk < 8192) {
        const float* in; bf16* out; int C, id;
        if (blk < 5120)      { in = Wq;  out = WqkvT;                C = 1024; id = blk - 4096; }
        else if (blk < 7168) { in = Wkv; out = WqkvT + 1024 * 1024;  C = 2048; id = blk - 5120; }
        else                 { in = Wo;  out = WoT;                  C = 1024; id = blk - 7168; }
        const int R = 1024;
        const int nbx = C / 32;
        const int j0 = (id % nbx) * 32, i0 = (id / nbx) * 32;
        const int tx = tid & 31, ty = tid >> 5;
        __shared__ float t[32][33];
        for (int r = ty; r < 32; r += 8)
            t[r][tx] = in[(size_t)(i0 + r) * C + j0 + tx];
        __syncthreads();
        for (int r = ty; r < 32; r += 8)
            out[(size_t)(j0 + r) * R + i0 + tx] = (bf16)t[tx][r];
        return;
    }
    int i = (blk - 8192) * 256 + tid;
    if (i < 3072) bqkv[i] = (i < 1024) ? bq[i] : bkv[i - 1024];
}

// ---------------------------------------------------------------------------
// GEMM v2 (round-8 verified, verbatim): m97-structure + T3-minimum 2-phase +
// T1 XCD grid swizzle. Double-buffered LDS; counted vmcnt; lgkmcnt(0) drain
// before the loop-end barrier. (Counted vmcnt is safe HERE: acc state is
// small, kernel compiles ~160 VGPR, no spill. Session invariant: counted
// vmcnt + register spills is a correctness poison — spill buffer ops
// increment vmcnt and under-count the wait. Do not raise tile/BK sizes
// without re-checking VGPR; BK=64 also regresses occupancy per m132.)
// ---------------------------------------------------------------------------
template <int BM, int BN, int EPI>
__global__ __launch_bounds__(256) void gemm2_kernel(const bf16* __restrict__ A,
                                                    const bf16* __restrict__ BT,
                                                    const float* __restrict__ bias,
                                                    bf16* __restrict__ oQ,
                                                    bf16* __restrict__ oK,
                                                    bf16* __restrict__ oVT,
                                                    float* __restrict__ oF, int K) {
    constexpr int WM = BM / 2, WN = BN / 2;
    constexpr int MT = WM / 16, NT = WN / 16;
    constexpr int NLD = BM / 64 + BN / 64;   // global_load_lds per thread/step

    const int tid = threadIdx.x;
    const int lane = tid & 63, wid = tid >> 6;
    const int l15 = lane & 15, quad = lane >> 4;
    const int wm = (wid >> 1) * WM, wn = (wid & 1) * WN;

    // XCD-aware swizzle: lid -> wg (bijective; nwg%8==0 for 768 and 512).
    const int lid = blockIdx.y * gridDim.x + blockIdx.x;
    const int per = (gridDim.x * gridDim.y) >> 3;
    const int wg = (lid & 7) * per + (lid >> 3);
    const int m0 = (wg / gridDim.x) * BM, n0 = (wg % gridDim.x) * BN;

    __shared__ bf16 As[2][BM * 32];
    __shared__ bf16 Bs[2][BN * 32];

    f32x4 acc[MT][NT] = {};

    const bf16* Ag = A + (size_t)m0 * K;
    const bf16* Bg = BT + (size_t)n0 * K;
    const int arow = lane >> 2, acol = (lane & 3) * 8;

#define GSTAGE(buf, k0v) {                                                   \
        _Pragma("unroll")                                                    \
        for (int t = 0; t < BM / 64; ++t) {                                  \
            int tt = t * 4 + wid;                                            \
            load_lds16(Ag + (size_t)(tt * 16 + arow) * K + (k0v) + acol,     \
                       &As[buf][tt * 512]);                                  \
        }                                                                    \
        _Pragma("unroll")                                                    \
        for (int t = 0; t < BN / 64; ++t) {                                  \
            int tt = t * 4 + wid;                                            \
            load_lds16(Bg + (size_t)(tt * 16 + arow) * K + (k0v) + acol,     \
                       &Bs[buf][tt * 512]);                                  \
        }                                                                    \
    }

    GSTAGE(0, 0)

    const int NSTEP = K >> 5;
    for (int s = 0; s < NSTEP; ++s) {
        const int cur = s & 1;
        if (s < NSTEP - 1) {
            GSTAGE(cur ^ 1, (s + 1) * 32)
            // wait only for step s's loads; step s+1's NLD stay in flight
            if constexpr (NLD == 4)
                asm volatile("s_waitcnt vmcnt(4)" ::: "memory");
            else if constexpr (NLD == 3)
                asm volatile("s_waitcnt vmcnt(3)" ::: "memory");
            else
                asm volatile("s_waitcnt vmcnt(2)" ::: "memory");
        } else {
            asm volatile("s_waitcnt vmcnt(0)" ::: "memory");
        }
        __builtin_amdgcn_s_barrier();

        bf16x8 af[MT], bfr[NT];
#pragma unroll
        for (int i = 0; i < MT; ++i)
            af[i] = *(const bf16x8*)&As[cur][(wm + i * 16 + l15) * 32 + quad * 8];
#pragma unroll
        for (int j = 0; j < NT; ++j)
            bfr[j] = *(const bf16x8*)&Bs[cur][(wn + j * 16 + l15) * 32 + quad * 8];
#pragma unroll
        for (int i = 0; i < MT; ++i)
#pragma unroll
            for (int j = 0; j < NT; ++j)
                acc[i][j] = MFMA16(af[i], bfr[j], acc[i][j]);

        // drain LDS reads before the barrier: next iteration's STAGE
        // overwrites buf[cur], and raw s_barrier alone doesn't drain lgkm.
        asm volatile("s_waitcnt lgkmcnt(0)" ::: "memory");
        __builtin_amdgcn_s_barrier();
    }
#undef GSTAGE

    // epilogue (C-layout: row = quad*4+r, col = l15)
#pragma unroll
    for (int i = 0; i < MT; ++i) {
#pragma unroll
        for (int j = 0; j < NT; ++j) {
            const int mb = m0 + wm + i * 16 + quad * 4;
            const int n = n0 + wn + j * 16 + l15;
            const float bv = bias[n];
            if (EPI == 2) {
                float* o = oF + (size_t)mb * 1024 + n;
#pragma unroll
                for (int r = 0; r < 4; ++r) o[(size_t)r * 1024] = acc[i][j][r] + bv;
            } else if (n0 < 1024) {
#pragma unroll
                for (int r = 0; r < 4; ++r)
                    oQ[(size_t)(mb + r) * 1024 + n] = (bf16)((acc[i][j][r] + bv) * CEXP);
            } else if (n0 < 2048) {
#pragma unroll
                for (int r = 0; r < 4; ++r)
                    oK[(size_t)(mb + r) * 1024 + (n - 1024)] = (bf16)(acc[i][j][r] + bv);
            } else {
                const int hd = n - 2048;
                const int bb = mb >> 11, ss = mb & 2047;
                bf16v4 pk;
#pragma unroll
                for (int r = 0; r < 4; ++r) pk[r] = (bf16)(acc[i][j][r] + bv);
                *(bf16v4*)&oVT[((size_t)(bb << 10) + hd) * 2048 + ss] = pk;
            }
        }
    }
}

// ---------------------------------------------------------------------------
// softmax of one 64-key half (two 32-key sacc tiles) -> 4 PV B-fragments.
// sacc reg r holds key32 = (r&3) + 8*(r>>2) + 4*hh; PV frag s covers keys
// 16s+8hh+j: words 0/2 = plswap(A[qa],A[qb]), words 1/3 = plswap(B[qa],B[qb]).
// ---------------------------------------------------------------------------
__device__ __forceinline__ void sm_half(f32x16 sa, f32x16 sb, float& l_lane,
                                        bf16x8* pf) {
    unsigned wA[2][4], wB[2][4];
#pragma unroll
    for (int m = 0; m < 2; ++m) {
        const f32x16 s = m ? sb : sa;
#pragma unroll
        for (int g = 0; g < 4; ++g) {
            float p0 = __builtin_amdgcn_exp2f(s[g * 4 + 0]);
            float p1 = __builtin_amdgcn_exp2f(s[g * 4 + 1]);
            float p2 = __builtin_amdgcn_exp2f(s[g * 4 + 2]);
            float p3 = __builtin_amdgcn_exp2f(s[g * 4 + 3]);
            l_lane += (p0 + p1) + (p2 + p3);
            wA[m][g] = cvtpk_bf16(p0, p1);
            wB[m][g] = cvtpk_bf16(p2, p3);
        }
    }
#pragma unroll
    for (int s = 0; s < 4; ++s) {
        const int m = s >> 1, qa = (s & 1) * 2, qb = qa + 1;
        unsigned x0 = wA[m][qa], x2 = wA[m][qb];
        unsigned x1 = wB[m][qa], x3 = wB[m][qb];
        plswap(x0, x2);
        plswap(x1, x3);
        u32x4 fw;
        fw[0] = x0; fw[1] = x1; fw[2] = x2; fw[3] = x3;
        pf[s] = __builtin_bit_cast(bf16x8, fw);
    }
}

// ---------------------------------------------------------------------------
// Flash attention v8 (twice-verified: rounds 2/4/8, ~52.3 µs): intra-wave
// pipe overlap, 4 waves/block, 2 waves/SIMD.
// Session evidence log for future iterations on this kernel:
//  - TLP is NOT the bottleneck (r7: 4 blocks/CU resident -> no occupancy or
//    speed gain; the residual ~25% dead-issue is dependency-serial).
//  - Bank conflicts are off the critical path (r1: halving them changed 0).
//  - Cross-iteration software pipelines (defer sm1+PV1 into kt+1, r9/r10)
//    fail correctness nondeterministically even with full vmcnt(0) drains
//    and sched_barrier(0) fences; un-shippable without a single-variant
//    disasm + race-screen loop.
//  - Counted vmcnt + spills is a correctness poison (r6/r9 diagnosis):
//    this kernel must stay spill-free (VGPR 128, verified).
// ---------------------------------------------------------------------------
__global__ __launch_bounds__(256) void attn8_kernel(const bf16* __restrict__ Q,
                                                    const bf16* __restrict__ K,
                                                    const bf16* __restrict__ VT,
                                                    bf16* __restrict__ O) {
    const int bid = blockIdx.x;
    const int xcd = bid & 7, j = bid >> 3;
    const int bh = xcd * 4 + (j >> 4);        // per-XCD bh stripe
    const int q0 = (j & 15) * 128;
    const int b = bh >> 4, head = bh & 15;
    const int tid = threadIdx.x;
    const int lane = tid & 63, wid = tid >> 6;
    const int l31 = lane & 31, hh = lane >> 5;

    __shared__ bf16 Ks[2][128 * 64];    // [buf][key][d]   row = 128B, XOR-swizzled
    __shared__ bf16 VTs[2][64 * 128];   // [buf][d][key]   row = 256B, XOR-swizzled

    // Q B-frags: B[k=d][n=q]: n = lane&31, k = kd*16 + hh*8 + j
    const int qw = q0 + wid * 32;
    bf16x8 qf[4];
#pragma unroll
    for (int kd = 0; kd < 4; ++kd)
        qf[kd] = *(const bf16x8*)&Q[(size_t)(b * SLEN + qw + l31) * HDIM +
                                    head * 64 + kd * 16 + hh * 8];

    f32x16 o_acc[2] = {};
    const f32x16 ZC = {};   // persistent zero C-operand for QK chain heads
    float l_lane = 0.f;

    const bf16* Kg = K + (size_t)b * SLEN * HDIM + head * 64;
    const bf16* Vg = VT + (size_t)bh * 64 * SLEN;

    // staging lane geometry
    const int r8 = lane >> 3, p8 = lane & 7;     // K: 8 rows x 8 chunks / instr
    const int r16 = lane >> 4, p16 = lane & 15;  // V: 4 rows x 16 chunks / instr

    // barrier-convoy desync between the two co-resident blocks per CU:
    // rotate the key-tile walk (key order is sum-commutative).
    const int ph = (j & 1) << 3;

#define STAGE(buf, ktv) {                                                          \
        const int k0_ = (((ktv) + ph) & 15) * 128;                                 \
        _Pragma("unroll")                                                          \
        for (int pass = 0; pass < 4; ++pass) {                                     \
            const int rbk = pass * 32 + wid * 8;                                   \
            load_lds16(Kg + (size_t)(k0_ + rbk + r8) * HDIM +                      \
                           ((p8 ^ ((rbk + r8) & 7)) * 8),                          \
                       &Ks[buf][rbk * 64]);                                        \
            const int rbv = pass * 16 + wid * 4;                                   \
            load_lds16(Vg + (size_t)(rbv + r16) * SLEN + k0_ +                     \
                           ((p16 ^ ((rbv + r16) & 15)) * 8),                       \
                       &VTs[buf][rbv * 128]);                                      \
        } }

    STAGE(0, 0)

    for (int kt = 0; kt < 16; ++kt) {
        const int cur = kt & 1;
        if (kt < 15) {
            STAGE(cur ^ 1, kt + 1)
            asm volatile("s_waitcnt vmcnt(8)" ::: "memory");
        } else {
            asm volatile("s_waitcnt vmcnt(0)" ::: "memory");
        }
        __builtin_amdgcn_s_barrier();

        const bf16* Kc = &Ks[cur][0];
        const bf16* Vc = &VTs[cur][0];

        // ---- QK^T, BOTH 64-key halves up front (4 independent chains) ----
        f32x16 s00, s01, s10, s11;
        __builtin_amdgcn_s_setprio(1);
#define QK_STEP(sv, h, m, kd, Cin) {                                       \
        const int key_ = ((h) * 2 + (m)) * 32 + l31;                       \
        const int c_ = ((kd) * 2 + hh) ^ (key_ & 7);                       \
        bf16x8 kf_ = *(const bf16x8*)&Kc[key_ * 64 + c_ * 8];              \
        sv = MFMA32(kf_, qf[kd], Cin); }
        QK_STEP(s00, 0, 0, 0, ZC)
        QK_STEP(s01, 0, 1, 0, ZC)
        QK_STEP(s10, 1, 0, 0, ZC)
        QK_STEP(s11, 1, 1, 0, ZC)
#pragma unroll
        for (int kd = 1; kd < 4; ++kd) {
            QK_STEP(s00, 0, 0, kd, s00)
            QK_STEP(s01, 0, 1, kd, s01)
            QK_STEP(s10, 1, 0, kd, s10)
            QK_STEP(s11, 1, 1, kd, s11)
        }
        __builtin_amdgcn_s_setprio(0);

        // ---- softmax h=0 (VALU) under QK h=1 MFMA drain ----
        bf16x8 pf0[4], pf1[4];
        sm_half(s00, s01, l_lane, pf0);

        // ---- PV h=0 (8 MFMA) ----
        __builtin_amdgcn_s_setprio(1);
#pragma unroll
        for (int s = 0; s < 4; ++s)
#pragma unroll
            for (int dt = 0; dt < 2; ++dt) {
                const int d = dt * 32 + l31;
                const int cc = (s * 2 + hh) ^ (d & 15);
                bf16x8 vf = *(const bf16x8*)&Vc[d * 128 + cc * 8];
                o_acc[dt] = MFMA32(vf, pf0[s], o_acc[dt]);
            }
        __builtin_amdgcn_s_setprio(0);

        // ---- softmax h=1 (VALU) under PV h=0 MFMA drain ----
        sm_half(s10, s11, l_lane, pf1);

        // ---- PV h=1 (8 MFMA) ----
        __builtin_amdgcn_s_setprio(1);
#pragma unroll
        for (int s = 0; s < 4; ++s)
#pragma unroll
            for (int dt = 0; dt < 2; ++dt) {
                const int d = dt * 32 + l31;
                const int cc = ((4 + s) * 2 + hh) ^ (d & 15);
                bf16x8 vf = *(const bf16x8*)&Vc[d * 128 + cc * 8];
                o_acc[dt] = MFMA32(vf, pf1[s], o_acc[dt]);
            }
        __builtin_amdgcn_s_setprio(0);

        asm volatile("" ::: "memory");
        __builtin_amdgcn_s_barrier();
    }

    // epilogue: l = own half + other key-half (lane^32 has same query col)
    const float l_full = l_lane + __shfl_xor(l_lane, 32, 64);
    const float inv = 1.f / l_full;
    bf16* orow = O + (size_t)(b * SLEN + qw + l31) * HDIM + head * 64;
#pragma unroll
    for (int mt = 0; mt < 2; ++mt)
#pragma unroll
        for (int g = 0; g < 4; ++g) {
            bf16v4 pk;
#pragma unroll
            for (int r = 0; r < 4; ++r) pk[r] = (bf16)(o_acc[mt][g * 4 + r] * inv);
            *(bf16v4*)&orow[mt * 32 + g * 8 + 4 * hh] = pk;
        }
}

// ---------------------------------------------------------------------------
// launch
// ---------------------------------------------------------------------------
extern "C" void kernel_launch(void* const* d_in, const int* in_sizes, int n_in,
                              void* d_out, int out_size, void* d_ws, size_t ws_size,
                              hipStream_t stream) {
    const float* X   = (const float*)d_in[0];
    const float* Wq  = (const float*)d_in[1];
    const float* bq  = (const float*)d_in[2];
    const float* Wkv = (const float*)d_in[3];
    const float* bkv = (const float*)d_in[4];
    const float* Wo  = (const float*)d_in[5];
    const float* bo  = (const float*)d_in[6];
    float* out = (float*)d_out;

    char* ws = (char*)d_ws;
    bf16* Xbf   = (bf16*)(ws);                     // 8 MB  (4096x1024)
    bf16* WqkvT = (bf16*)(ws + (8ull << 20));      // 6 MB  (3072x1024)
    bf16* WoT   = (bf16*)(ws + (14ull << 20));     // 2 MB  (1024x1024)
    float* bqkv = (float*)(ws + (16ull << 20));    // 12 KB (3072)
    bf16* Qbf   = (bf16*)(ws + (17ull << 20));     // 8 MB (pre-scaled by CEXP)
    bf16* Kbf   = (bf16*)(ws + (25ull << 20));     // 8 MB
    bf16* VTbf  = (bf16*)(ws + (33ull << 20));     // 8 MB (per-head transposed V)
    bf16* Abf   = (bf16*)(ws + (41ull << 20));     // 8 MB

    // merged prep (1 launch)
    prep_kernel<<<8204, 256, 0, stream>>>(X, Wq, Wkv, Wo, bq, bkv, Xbf, WqkvT, WoT, bqkv);

    // fused QKV projection: (4096x1024) @ (1024x3072), 2-phase + XCD swizzle
    gemm2_kernel<128, 128, 1><<<dim3(3072 / 128, MROWS / 128), 256, 0, stream>>>(
        Xbf, WqkvT, bqkv, Qbf, Kbf, VTbf, nullptr, 1024);

    // flash attention (verified v8)
    attn8_kernel<<<512, 256, 0, stream>>>(Qbf, Kbf, VTbf, Abf);

    // output projection: (4096x1024) @ (1024x1024) + bo -> fp32, 2-phase + swizzle
    gemm2_kernel<128, 64, 2><<<dim3(1024 / 64, MROWS / 128), 256, 0, stream>>>(
        Abf, WoT, bo, nullptr, nullptr, nullptr, out, 1024);
}